// Round 5
// baseline (303.976 us; speedup 1.0000x reference)
//
#include <hip/hip_runtime.h>

#define B_ROWS 8192
#define WIDTH  512
#define DEPTH  7
#define CIN    4096
#define EPS    1e-5f
#define SLOPE  0.01f

typedef __attribute__((ext_vector_type(8))) short short8;
typedef __attribute__((ext_vector_type(4))) short short4v;
typedef __attribute__((ext_vector_type(4))) float f32x4;
typedef __attribute__((ext_vector_type(16))) float f32x16;

// round-to-nearest-even f32 -> bf16 bits
__device__ inline short f2bf(float f) {
  unsigned u = __builtin_bit_cast(unsigned, f);
  unsigned r = (u + 0x7FFFu + ((u >> 16) & 1u)) >> 16;
  return (short)r;
}

__device__ inline void gl_lds16(const void* g, void* l) {
  __builtin_amdgcn_global_load_lds(
      (const __attribute__((address_space(1))) unsigned*)g,
      (__attribute__((address_space(3))) unsigned*)l, 16, 0, 0);
}

// ---------------- weight conversion: 7 fp32 W's -> packed bf16 ----------------
struct WP { const float* p[7]; };

__global__ __launch_bounds__(256) void convw(WP wp, short* __restrict__ out) {
  long e = ((long)blockIdx.x * 256 + threadIdx.x) * 4;  // 4 elems/thread
  int layer; long base;
  if      (e < 262144L)  { layer = 0; base = 0; }
  else if (e < 786432L)  { layer = 1; base = 262144L; }
  else if (e < 1572864L) { layer = 2; base = 786432L; }
  else if (e < 2621440L) { layer = 3; base = 1572864L; }
  else if (e < 3932160L) { layer = 4; base = 2621440L; }
  else if (e < 5505024L) { layer = 5; base = 3932160L; }
  else                   { layer = 6; base = 5505024L; }
  f32x4 v = *(const f32x4*)(wp.p[layer] + (e - base));
  short4v o;
  o.x = f2bf(v.x); o.y = f2bf(v.y); o.z = f2bf(v.z); o.w = f2bf(v.w);
  *(short4v*)(out + e) = o;
}

// -------- x -> bf16 concat buffer + classifier partial (+ zero sums) ----------
__global__ __launch_bounds__(256) void initx(const float* __restrict__ x,
                                             const float* __restrict__ wc,
                                             short* __restrict__ lastbf,
                                             float* __restrict__ logit,
                                             float* __restrict__ sumsz) {
  int gid = blockIdx.x * 256 + threadIdx.x;
  if (gid < DEPTH * 1024) sumsz[gid] = 0.f;  // zero all layers' stats buffers
  int w = threadIdx.x >> 6, l = threadIdx.x & 63;
  int r = blockIdx.x * 4 + w;
  const float* xr = x + (long)r * 512 + l * 8;
  f32x4 v0 = *(const f32x4*)xr;
  f32x4 v1 = *(const f32x4*)(xr + 4);
  const float* wcr = wc + l * 8;
  float acc = 0.f;
  short8 ob;
#pragma unroll
  for (int j = 0; j < 4; ++j) { acc += v0[j] * wcr[j];     ob[j]     = f2bf(v0[j]); }
#pragma unroll
  for (int j = 0; j < 4; ++j) { acc += v1[j] * wcr[4 + j]; ob[4 + j] = f2bf(v1[j]); }
  *(short8*)&lastbf[(long)r * CIN + l * 8] = ob;
#pragma unroll
  for (int off = 32; off; off >>= 1) acc += __shfl_xor(acc, off);
  if (l == 0) logit[r] = acc;
}

// ---------------- bf16 MFMA GEMM + fused column stats -------------------------
// BM=128, BN=64, BK=64, grid (64,8) = 512 blocks -> 2 blocks/CU.
// 256 threads = 4 waves; wave ks owns a K-quarter (k16 slice of each BK=64
// tile), covers the FULL 128x64 tile with 32x32x16 MFMA (acc[4][2] f32x16).
// 3-stage software pipeline: tile t+2 staged at iter t (3 x 24KB LDS rotation);
// end-of-iter counted s_waitcnt vmcnt(6) (tile t+1, issued ~2 iters earlier)
// + raw s_barrier — prefetch loads stay in flight across barriers (T3/T4).
// XOR-swizzle (byte ^ ((row&7)<<4)) via pre-swizzled global source (rule #21).
// Epilogue: tree-combine partials in LDS (aliases staging), ks=0 writes C and
// atomically accumulates per-column sum/sumsq.
__global__ __launch_bounds__(256, 2) void gemm_fused(const short* __restrict__ A,
                                                     const short* __restrict__ Bw,
                                                     float* __restrict__ C,
                                                     float* __restrict__ sums,
                                                     int K) {
  __shared__ __align__(16) char smem[73728];  // 3 x (As 16KB + Bs 8KB)
  int t = threadIdx.x;
  int ks = t >> 6, l = t & 63;
  int l31 = l & 31, hi = l >> 5;
  int bm = blockIdx.x, bn = blockIdx.y;
  const short* Ab = A + (long)(bm * 128) * CIN;
  const short* Bb = Bw + (long)(bn * 64) * K;

  f32x16 acc[4][2];
#pragma unroll
  for (int m = 0; m < 4; ++m)
#pragma unroll
    for (int n = 0; n < 2; ++n)
#pragma unroll
      for (int r = 0; r < 16; ++r) acc[m][n][r] = 0.f;

  // staging: 24 x 1KB chunks/tile (A: 16, B: 8); wave ks stages A chunks
  // 4ks..4ks+3 and B chunks 2ks..2ks+1; dest row = chunk*8 + (l>>3); source
  // col pre-swizzled so read-side byte^((row&7)<<4) is the matching involution.
  int l8 = l >> 3;
  int scol = ((l & 7) ^ l8) << 3;
  const short* pA0 = Ab + (long)((ks * 4 + 0) * 8 + l8) * CIN + scol;
  const short* pA1 = Ab + (long)((ks * 4 + 1) * 8 + l8) * CIN + scol;
  const short* pA2 = Ab + (long)((ks * 4 + 2) * 8 + l8) * CIN + scol;
  const short* pA3 = Ab + (long)((ks * 4 + 3) * 8 + l8) * CIN + scol;
  const short* pB0 = Bb + (long)((ks * 2 + 0) * 8 + l8) * K + scol;
  const short* pB1 = Bb + (long)((ks * 2 + 1) * 8 + l8) * K + scol;

#define STAGE(base, k0)                                       \
  {                                                           \
    gl_lds16(pA0 + (k0), (base) + (ks * 4 + 0) * 1024);       \
    gl_lds16(pA1 + (k0), (base) + (ks * 4 + 1) * 1024);       \
    gl_lds16(pA2 + (k0), (base) + (ks * 4 + 2) * 1024);       \
    gl_lds16(pA3 + (k0), (base) + (ks * 4 + 3) * 1024);       \
    gl_lds16(pB0 + (k0), (base) + 16384 + (ks * 2 + 0) * 1024); \
    gl_lds16(pB1 + (k0), (base) + 16384 + (ks * 2 + 1) * 1024); \
  }

  // fragment k-slice: wave ks reads k-bytes [ks*32, ks*32+32); lane's 16B at
  // kb = ks*32 + hi*16, XOR'd with ((row&7)<<4) where row&7 == l&7.
  int kb = ks * 32 + hi * 16;
  int sw = (l & 7) << 4;

#define KITER(rb, sb, do_stage, k2, vmlit)                                     \
  {                                                                            \
    if (do_stage) STAGE((sb), (k2));                                           \
    const char* AsC = (rb);                                                    \
    const char* BsC = (rb) + 16384;                                            \
    short8 a[4], b[2];                                                         \
    _Pragma("unroll")                                                          \
    for (int m = 0; m < 4; ++m)                                                \
      a[m] = *(const short8*)(AsC + (m * 32 + l31) * 128 + (kb ^ sw));         \
    _Pragma("unroll")                                                          \
    for (int n = 0; n < 2; ++n)                                                \
      b[n] = *(const short8*)(BsC + (n * 32 + l31) * 128 + (kb ^ sw));         \
    __builtin_amdgcn_s_setprio(1);                                             \
    _Pragma("unroll")                                                          \
    for (int m = 0; m < 4; ++m)                                                \
      _Pragma("unroll")                                                        \
      for (int n = 0; n < 2; ++n)                                              \
        acc[m][n] = __builtin_amdgcn_mfma_f32_32x32x16_bf16(a[m], b[n],        \
                                                            acc[m][n], 0, 0, 0); \
    __builtin_amdgcn_s_setprio(0);                                             \
    asm volatile("s_waitcnt vmcnt(" #vmlit ")" ::: "memory");                  \
    __builtin_amdgcn_s_barrier();                                              \
  }

  char* buf0 = smem;
  char* buf1 = smem + 24576;
  char* buf2 = smem + 49152;

  STAGE(buf0, 0);
  STAGE(buf1, 64);
  asm volatile("s_waitcnt vmcnt(6)" ::: "memory");  // tile 0 resident
  __builtin_amdgcn_s_barrier();

  int nt = K >> 6;  // K is a multiple of 64; nt >= 8
  int tix = 0;
  for (; tix < nt - 2; ++tix) {
    KITER(buf0, buf2, true, ((tix + 2) << 6), 6);
    char* tmp = buf0; buf0 = buf1; buf1 = buf2; buf2 = tmp;
  }
  KITER(buf0, buf2, false, 0, 0);
  { char* tmp = buf0; buf0 = buf1; buf1 = buf2; buf2 = tmp; }
  KITER(buf0, buf2, false, 0, 0);

  // ---- tree-combine 4 K-quarters (aliases staging LDS), write C, stats ----
  float* Red0 = (float*)smem;             // 32KB
  float* Red1 = (float*)(smem + 32768);   // 32KB
#define RIDX(m, n, r) (((m) * 32 + ((r) & 3) + 8 * ((r) >> 2) + 4 * hi) * 64 + (n) * 32 + l31)
  if (ks == 1) {
#pragma unroll
    for (int m = 0; m < 4; ++m)
#pragma unroll
      for (int n = 0; n < 2; ++n)
#pragma unroll
        for (int r = 0; r < 16; ++r) Red0[RIDX(m, n, r)] = acc[m][n][r];
  }
  if (ks == 3) {
#pragma unroll
    for (int m = 0; m < 4; ++m)
#pragma unroll
      for (int n = 0; n < 2; ++n)
#pragma unroll
        for (int r = 0; r < 16; ++r) Red1[RIDX(m, n, r)] = acc[m][n][r];
  }
  __syncthreads();
  if (ks == 2) {
#pragma unroll
    for (int m = 0; m < 4; ++m)
#pragma unroll
      for (int n = 0; n < 2; ++n)
#pragma unroll
        for (int r = 0; r < 16; ++r) {
          float v = acc[m][n][r] + Red1[RIDX(m, n, r)];
          Red1[RIDX(m, n, r)] = v;
        }
  }
  __syncthreads();
  if (ks == 0) {
    float* Cb = C + (long)(bm * 128) * WIDTH + bn * 64;
#pragma unroll
    for (int n = 0; n < 2; ++n) {
      float s = 0.f, q = 0.f;
#pragma unroll
      for (int m = 0; m < 4; ++m) {
#pragma unroll
        for (int r = 0; r < 16; ++r) {
          int cr = (r & 3) + 8 * (r >> 2) + 4 * hi;
          float v = acc[m][n][r] + Red0[RIDX(m, n, r)] + Red1[RIDX(m, n, r)];
          Cb[(long)(m * 32 + cr) * WIDTH + n * 32 + l31] = v;
          s += v; q += v * v;
        }
      }
      s += __shfl_xor(s, 32);
      q += __shfl_xor(q, 32);
      if (l < 32) {
        int colg = bn * 64 + n * 32 + l;
        atomicAdd(&sums[colg], s);
        atomicAdd(&sums[WIDTH + colg], q);
      }
    }
  }
#undef RIDX
#undef KITER
#undef STAGE
}

// ---------------- BN + LeakyReLU + noise + classifier partial + bf16 store ----
__global__ __launch_bounds__(256) void bnact(const float* __restrict__ h,
                                             const float* __restrict__ sums,
                                             const float* __restrict__ gamma,
                                             const float* __restrict__ beta,
                                             const float* __restrict__ noise,
                                             const float* __restrict__ wc,
                                             short* __restrict__ lastseg,
                                             float* __restrict__ logit) {
  int w = threadIdx.x >> 6, l = threadIdx.x & 63;
  int r = blockIdx.x * 4 + w;
  int c = l * 8;
  const float invB = 1.0f / 8192.0f;
  f32x4 h0 = *(const f32x4*)&h[(long)r * WIDTH + c];
  f32x4 h1 = *(const f32x4*)&h[(long)r * WIDTH + c + 4];
  f32x4 n0 = *(const f32x4*)&noise[(long)r * WIDTH + c];
  f32x4 n1 = *(const f32x4*)&noise[(long)r * WIDTH + c + 4];
  float acc = 0.f;
  short8 ob;
#pragma unroll
  for (int j = 0; j < 8; ++j) {
    int cc = c + j;
    float hv = j < 4 ? h0[j] : h1[j - 4];
    float nv = j < 4 ? n0[j] : n1[j - 4];
    float mean = sums[cc] * invB;
    float var = sums[WIDTH + cc] * invB - mean * mean;
    float v = (hv - mean) * rsqrtf(var + EPS);
    v = v * gamma[cc] + beta[cc];
    v = v >= 0.f ? v : SLOPE * v;
    v *= nv;
    acc += v * wc[cc];
    ob[j] = f2bf(v);
  }
  *(short8*)&lastseg[(long)r * CIN + c] = ob;
#pragma unroll
  for (int off = 32; off; off >>= 1) acc += __shfl_xor(acc, off);
  if (l == 0) logit[r] += acc;  // one wave per row: no race
}

// ---------------- sigmoid ----------------------------------------------------
__global__ __launch_bounds__(256) void finalize(const float* __restrict__ logit,
                                                const float* __restrict__ bc,
                                                float* __restrict__ out) {
  int i = blockIdx.x * 256 + threadIdx.x;
  float z = logit[i] + bc[0];
  out[i] = 1.0f / (1.0f + expf(-z));
}

extern "C" void kernel_launch(void* const* d_in, const int* in_sizes, int n_in,
                              void* d_out, int out_size, void* d_ws, size_t ws_size,
                              hipStream_t stream) {
  (void)in_sizes; (void)n_in; (void)out_size; (void)ws_size;
  const float* x     = (const float*)d_in[0];
  WP wp;
  for (int i = 0; i < 7; ++i) wp.p[i] = (const float*)d_in[1 + i];
  // d_in[8] = b (linear bias) — cancels exactly through training-mode BN; unused.
  const float* gamma = (const float*)d_in[9];
  const float* beta  = (const float*)d_in[10];
  const float* Wc    = (const float*)d_in[11];
  const float* bc    = (const float*)d_in[12];
  const float* noise = (const float*)d_in[13];

  char* ws = (char*)d_ws;
  short* lastbf = (short*)ws;                               // 8192*4096 bf16 = 64 MiB
  float* hpre   = (float*)(ws + 67108864);                  // 8192*512 f32  = 16 MiB
  short* wbf    = (short*)(ws + 67108864 + 16777216);       // 7.34M bf16    = 14 MiB
  float* sums   = (float*)(ws + 67108864 + 16777216 + 14680064);   // 7*1024 f32
  float* logit  = (float*)(ws + 67108864 + 16777216 + 14680064 + 28672);  // 8192 f32

  convw<<<7168, 256, 0, stream>>>(wp, wbf);
  initx<<<2048, 256, 0, stream>>>(x, Wc, lastbf, logit, sums);

  long woff = 0;
  for (int i = 0; i < DEPTH; ++i) {
    int K = 512 * (i + 1);
    gemm_fused<<<dim3(64, 8), 256, 0, stream>>>(lastbf, wbf + woff, hpre,
                                                sums + i * 1024, K);
    bnact<<<2048, 256, 0, stream>>>(hpre, sums + i * 1024,
                                    gamma + i * 512, beta + i * 512,
                                    noise + (long)i * B_ROWS * WIDTH,
                                    Wc + 512 + i * 512,
                                    lastbf + 512 + (long)i * 512, logit);
    woff += (long)512 * K;
  }
  finalize<<<32, 256, 0, stream>>>(logit, bc, (float*)d_out);
}